// Round 5
// baseline (41.958 us; speedup 1.0000x reference)
//
#include <hip/hip_runtime.h>

// Problem constants (from reference setup_inputs)
#define BB 4
#define CC 128
#define HH 192
#define WW 256
#define HW (HH * WW)

// Fused kernel: per-pixel channel reductions -> clamped normalized dot
// Dc[b,h,w] = max(dot/(|i||e|), 0), then SCATTER Dc to its 9 output
// positions: out[b,(i,j),h+1-i,w+1-j] = Dc[b,h,w] (valid targets only).
// Border targets (invalid source) are pre-zeroed by hipMemsetAsync.
// Block = 64 pixels (16 float4-quads) x 16 channel-chunks of 8 channels.
__global__ __launch_bounds__(256) void dotscatter_kernel(
    const float* __restrict__ img, const float* __restrict__ evt,
    float* __restrict__ out)
{
    const int blk = blockIdx.x;            // (b*H + h)*4 + seg
    const int tid = threadIdx.x;
    const int qx  = tid & 15;              // quad within 64-pixel segment
    const int cz  = tid >> 4;              // channel chunk 0..15
    const int seg = blk & 3;
    const int row = blk >> 2;              // b*H + h
    const int b   = row / HH;
    const int h   = row - b * HH;
    const int w0  = seg * 64 + (qx << 2);
    const int base0 = b * CC * HW + h * WW + w0;
    const int cbase = cz * 8;

    float4 aii = make_float4(0.f, 0.f, 0.f, 0.f);
    float4 aee = make_float4(0.f, 0.f, 0.f, 0.f);
    float4 aie = make_float4(0.f, 0.f, 0.f, 0.f);

    #pragma unroll
    for (int c = 0; c < 8; ++c) {
        const float4 iv = *reinterpret_cast<const float4*>(img + base0 + (cbase + c) * HW);
        const float4 ev = *reinterpret_cast<const float4*>(evt + base0 + (cbase + c) * HW);
        aii.x += iv.x * iv.x; aii.y += iv.y * iv.y; aii.z += iv.z * iv.z; aii.w += iv.w * iv.w;
        aee.x += ev.x * ev.x; aee.y += ev.y * ev.y; aee.z += ev.z * ev.z; aee.w += ev.w * ev.w;
        aie.x += iv.x * ev.x; aie.y += iv.y * ev.y; aie.z += iv.z * ev.z; aie.w += iv.w * ev.w;
    }

    __shared__ float s_ii[16][64];
    __shared__ float s_ee[16][64];
    __shared__ float s_ie[16][64];
    const int p4 = qx << 2;
    s_ii[cz][p4 + 0] = aii.x; s_ii[cz][p4 + 1] = aii.y; s_ii[cz][p4 + 2] = aii.z; s_ii[cz][p4 + 3] = aii.w;
    s_ee[cz][p4 + 0] = aee.x; s_ee[cz][p4 + 1] = aee.y; s_ee[cz][p4 + 2] = aee.z; s_ee[cz][p4 + 3] = aee.w;
    s_ie[cz][p4 + 0] = aie.x; s_ie[cz][p4 + 1] = aie.y; s_ie[cz][p4 + 2] = aie.z; s_ie[cz][p4 + 3] = aie.w;
    __syncthreads();

    if (tid < 64) {
        float ii = 0.f, ee = 0.f, ie = 0.f;
        #pragma unroll
        for (int k = 0; k < 16; ++k) {
            ii += s_ii[k][tid];
            ee += s_ee[k][tid];
            ie += s_ie[k][tid];
        }
        const float ni = fmaxf(sqrtf(ii), 1e-12f);
        const float ne = fmaxf(sqrtf(ee), 1e-12f);
        const float dc = fmaxf(ie / (ni * ne), 0.0f);   // ReLU folded

        const int w  = seg * 64 + tid;
        const int ob = b * 9;
        #pragma unroll
        for (int i = 0; i < 3; ++i) {
            const int th = h + 1 - i;                   // uniform across lanes
            if (th < 0 || th >= HH) continue;
            #pragma unroll
            for (int j = 0; j < 3; ++j) {
                const int tw = w + 1 - j;               // per-lane predicate
                if (tw >= 0 && tw < WW) {
                    __builtin_nontemporal_store(
                        dc, out + (((ob + i * 3 + j) * HH + th) * WW + tw));
                }
            }
        }
    }
}

extern "C" void kernel_launch(void* const* d_in, const int* in_sizes, int n_in,
                              void* d_out, int out_size, void* d_ws, size_t ws_size,
                              hipStream_t stream) {
    const float* img = (const float*)d_in[0];
    const float* evt = (const float*)d_in[1];
    float* out = (float*)d_out;

    // Zero the output first: scatter only writes valid-source positions;
    // border positions (invalid source) must be 0. Async memset is a valid
    // graph-capture node.
    hipMemsetAsync(out, 0, (size_t)out_size * sizeof(float), stream);

    dotscatter_kernel<<<BB * HH * 4, 256, 0, stream>>>(img, evt, out);
}

// Round 6
// 34.990 us; speedup vs baseline: 1.1991x; 1.1991x over previous
//
#include <hip/hip_runtime.h>

// Problem constants (from reference setup_inputs)
#define BB 4
#define CC 128
#define HH 192
#define WW 256
#define HW (HH * WW)

typedef float floatx4 __attribute__((ext_vector_type(4)));

// Fully fused: block = one image row (b,h). 512 threads = 64 pixel-quads x
// 8 channel-chunks of 16. Compute Dc[h,:] = max(dot/(|i||e|),0) for the whole
// row into LDS, then scatter the 9 shifted output rows (column shift gathered
// from LDS so every store is an aligned, coalesced float4).
__global__ __launch_bounds__(512) void fused_kernel(
    const float* __restrict__ img, const float* __restrict__ evt,
    float* __restrict__ out)
{
    const int row = blockIdx.x;            // b*H + h
    const int tid = threadIdx.x;
    const int qx  = tid & 63;              // pixel quad (cols qx*4 .. qx*4+3)
    const int cz  = tid >> 6;              // channel chunk 0..7 (== wave id)
    const int b   = row / HH;
    const int h   = row - b * HH;
    const int base0 = b * CC * HW + h * WW + (qx << 2);

    const float* ip = img + base0 + (cz * 16) * HW;
    const float* ep = evt + base0 + (cz * 16) * HW;

    floatx4 aii = 0.f, aee = 0.f, aie = 0.f;
    #pragma unroll
    for (int c = 0; c < 16; ++c) {
        const floatx4 iv = *reinterpret_cast<const floatx4*>(ip + c * HW);
        const floatx4 ev = *reinterpret_cast<const floatx4*>(ep + c * HW);
        aii += iv * iv;
        aee += ev * ev;
        aie += iv * ev;
    }

    __shared__ float s_ii[8][256];
    __shared__ float s_ee[8][256];
    __shared__ float s_ie[8][256];
    __shared__ float s_dc[256];
    const int p4 = qx << 2;
    s_ii[cz][p4 + 0] = aii.x; s_ii[cz][p4 + 1] = aii.y; s_ii[cz][p4 + 2] = aii.z; s_ii[cz][p4 + 3] = aii.w;
    s_ee[cz][p4 + 0] = aee.x; s_ee[cz][p4 + 1] = aee.y; s_ee[cz][p4 + 2] = aee.z; s_ee[cz][p4 + 3] = aee.w;
    s_ie[cz][p4 + 0] = aie.x; s_ie[cz][p4 + 1] = aie.y; s_ie[cz][p4 + 2] = aie.z; s_ie[cz][p4 + 3] = aie.w;
    __syncthreads();

    if (tid < 256) {
        float ii = 0.f, ee = 0.f, ie = 0.f;
        #pragma unroll
        for (int k = 0; k < 8; ++k) {
            ii += s_ii[k][tid];
            ee += s_ee[k][tid];
            ie += s_ie[k][tid];
        }
        const float ni = fmaxf(sqrtf(ii), 1e-12f);
        const float ne = fmaxf(sqrtf(ee), 1e-12f);
        s_dc[tid] = fmaxf(ie / (ni * ne), 0.0f);   // ReLU folded
    }
    __syncthreads();

    // Scatter: out[b, p=(i,j), th=h+1-i, tw] = s_dc[tw + j - 1] (0 outside).
    // 9 planes x 64 quads = 576 aligned float4 stores, spread over 512 threads.
    const size_t obase = (size_t)b * 9 * HH * WW;
    for (int q = tid; q < 576; q += 512) {
        const int p  = q >> 6;
        const int i  = p / 3;
        const int j  = p - 3 * i;
        const int th = h + 1 - i;
        if (th < 0 || th >= HH) continue;       // covered by edge blocks below
        const int c0 = (q & 63) << 2;
        float t[4];
        #pragma unroll
        for (int e = 0; e < 4; ++e) {
            const int sc = c0 + e + j - 1;
            t[e] = (sc >= 0 && sc < WW) ? s_dc[sc] : 0.0f;
        }
        floatx4 v = {t[0], t[1], t[2], t[3]};
        __builtin_nontemporal_store(
            v, reinterpret_cast<floatx4*>(out + obase + ((size_t)p * HH + th) * WW + c0));
    }
    // Border rows with no valid source: plane(i=0,*) row 0, plane(i=2,*) row H-1.
    if (h == 0) {
        const floatx4 z = 0.f;
        for (int q = tid; q < 192; q += 512) {
            const int p  = q >> 6;               // planes 0,1,2
            const int c0 = (q & 63) << 2;
            __builtin_nontemporal_store(
                z, reinterpret_cast<floatx4*>(out + obase + (size_t)p * HH * WW + c0));
        }
    }
    if (h == HH - 1) {
        const floatx4 z = 0.f;
        for (int q = tid; q < 192; q += 512) {
            const int p  = 6 + (q >> 6);         // planes 6,7,8
            const int c0 = (q & 63) << 2;
            __builtin_nontemporal_store(
                z, reinterpret_cast<floatx4*>(out + obase + ((size_t)p * HH + (HH - 1)) * WW + c0));
        }
    }
}

extern "C" void kernel_launch(void* const* d_in, const int* in_sizes, int n_in,
                              void* d_out, int out_size, void* d_ws, size_t ws_size,
                              hipStream_t stream) {
    const float* img = (const float*)d_in[0];
    const float* evt = (const float*)d_in[1];
    float* out = (float*)d_out;

    fused_kernel<<<BB * HH, 512, 0, stream>>>(img, evt, out);
}